// Round 3
// baseline (9676.315 us; speedup 1.0000x reference)
//
#include <hip/hip_runtime.h>
#include <math.h>

#define NBLOCKS 256
#define NTHREADS 256
#define HDIM 4096
#define NPAIR (HDIM/2)        // 2048 f16x2 pairs

typedef _Float16 f16x2  __attribute__((ext_vector_type(2)));
typedef _Float16 f16x16 __attribute__((ext_vector_type(16)));
typedef unsigned long long u64;

union UF { unsigned u; f16x2 h; };

__device__ __forceinline__ float dot2f(f16x2 a, f16x2 b, float c) {
  return __builtin_amdgcn_fdot2(a, b, c, false);   // v_dot2_f32_f16
}
__device__ __forceinline__ float sigmoidf_(float x) {
  return 1.0f / (1.0f + __expf(-x));
}
__device__ __forceinline__ float tanhf_(float x) {
  float a = fabsf(x);
  float t = __expf(-2.0f * a);
  float r = (1.0f - t) / (1.0f + t);
  return copysignf(r, x);
}
__device__ __forceinline__ void st64(u64* p, u64 v) {
  __hip_atomic_store(p, v, __ATOMIC_RELAXED, __HIP_MEMORY_SCOPE_AGENT);
}
__device__ __forceinline__ u64 ld64(const u64* p) {
  return __hip_atomic_load(p, __ATOMIC_RELAXED, __HIP_MEMORY_SCOPE_AGENT);
}

// ---- load one f16x16 chunk (8 f16x2 pairs, pair j at (const float2*)SRC + lane + 64*j) ----
#define LOAD_CHUNK(VAR, SRC, C) do {                                          \
  const float2* s_ = (const float2*)(SRC) + lane + 64 * ((C) * 8);            \
  float2 p0_ = s_[0];   float2 p1_ = s_[64];  float2 p2_ = s_[128];           \
  float2 p3_ = s_[192]; float2 p4_ = s_[256]; float2 p5_ = s_[320];           \
  float2 p6_ = s_[384]; float2 p7_ = s_[448];                                 \
  VAR = (f16x16){ (_Float16)p0_.x, (_Float16)p0_.y, (_Float16)p1_.x, (_Float16)p1_.y, \
                  (_Float16)p2_.x, (_Float16)p2_.y, (_Float16)p3_.x, (_Float16)p3_.y, \
                  (_Float16)p4_.x, (_Float16)p4_.y, (_Float16)p5_.x, (_Float16)p5_.y, \
                  (_Float16)p6_.x, (_Float16)p6_.y, (_Float16)p7_.x, (_Float16)p7_.y }; \
} while (0)

#define DECL_ROW(K) f16x16 w##K##_0, w##K##_1, w##K##_2, w##K##_3;

#define LOAD_ROW(K, GATE, IDX) do {                                           \
  const float* sr_ = W_hh + ((size_t)(GATE) * HDIM + (i0 + (IDX))) * HDIM;    \
  LOAD_CHUNK(w##K##_0, sr_, 0); LOAD_CHUNK(w##K##_1, sr_, 1);                 \
  LOAD_CHUNK(w##K##_2, sr_, 2); LOAD_CHUNK(w##K##_3, sr_, 3);                 \
} while (0)

#define PAIR(V, J) (__builtin_shufflevector((V), (V), 2 * (J), 2 * (J) + 1))

#define DOT8(K, C)                                                            \
  a##K = dot2f(PAIR(w##K##_##C, 0), hp0, a##K);                               \
  a##K = dot2f(PAIR(w##K##_##C, 1), hp1, a##K);                               \
  a##K = dot2f(PAIR(w##K##_##C, 2), hp2, a##K);                               \
  a##K = dot2f(PAIR(w##K##_##C, 3), hp3, a##K);                               \
  a##K = dot2f(PAIR(w##K##_##C, 4), hp4, a##K);                               \
  a##K = dot2f(PAIR(w##K##_##C, 5), hp5, a##K);                               \
  a##K = dot2f(PAIR(w##K##_##C, 6), hp6, a##K);                               \
  a##K = dot2f(PAIR(w##K##_##C, 7), hp7, a##K);

#define CHUNK_STEP(C) {                                                       \
  UF u0_, u1_, u2_, u3_, u4_, u5_, u6_, u7_;                                  \
  u0_.u = h_lds[lane + 64 * ((C) * 8 + 0)];                                   \
  u1_.u = h_lds[lane + 64 * ((C) * 8 + 1)];                                   \
  u2_.u = h_lds[lane + 64 * ((C) * 8 + 2)];                                   \
  u3_.u = h_lds[lane + 64 * ((C) * 8 + 3)];                                   \
  u4_.u = h_lds[lane + 64 * ((C) * 8 + 4)];                                   \
  u5_.u = h_lds[lane + 64 * ((C) * 8 + 5)];                                   \
  u6_.u = h_lds[lane + 64 * ((C) * 8 + 6)];                                   \
  u7_.u = h_lds[lane + 64 * ((C) * 8 + 7)];                                   \
  f16x2 hp0 = u0_.h, hp1 = u1_.h, hp2 = u2_.h, hp3 = u3_.h;                   \
  f16x2 hp4 = u4_.h, hp5 = u5_.h, hp6 = u6_.h, hp7 = u7_.h;                   \
  DOT8(0, C)  DOT8(1, C)  DOT8(2, C)  DOT8(3, C)                              \
  DOT8(4, C)  DOT8(5, C)  DOT8(6, C)  DOT8(7, C)                              \
  DOT8(8, C)  DOT8(9, C)  DOT8(10, C) DOT8(11, C)                             \
}

#define RED6(K)                                                               \
  _Pragma("unroll")                                                           \
  for (int o_ = 32; o_; o_ >>= 1) a##K += __shfl_xor(a##K, o_, 64);

#define GX_INIT(K, GATE, IDX) {                                               \
  const int row_ = (GATE) * HDIM + (i0 + (IDX));                              \
  const float* s_ = W_ih + (size_t)row_ * 400;                                \
  float acc_ = 0.0f;                                                          \
  for (int c = lane; c < 400; c += 64) acc_ += s_[c] * x_lds[c];              \
  _Pragma("unroll")                                                           \
  for (int o_ = 32; o_; o_ >>= 1) acc_ += __shfl_xor(acc_, o_, 64);           \
  acc_ += b_ih[row_];                                                         \
  if ((GATE) != 2) acc_ += b_hh[row_];                                        \
  gx##K = acc_;                                                               \
}

// 256 blocks x 256 threads (4 waves), 1 wave/SIMD, budget 512 VGPRs.
// Wave G (0..1023) owns h indices {4G..4G+3} = 12 W_hh rows = 384 weight VGPRs.
__global__ __launch_bounds__(NTHREADS, 1)
void gru_persistent(const float* __restrict__ start,
                    const float* __restrict__ enc_h,
                    const float* __restrict__ W_ih,
                    const float* __restrict__ W_hh,
                    const float* __restrict__ b_ih,
                    const float* __restrict__ b_hh,
                    const float* __restrict__ W_out,
                    const float* __restrict__ b_out,
                    float* __restrict__ out,
                    u64* __restrict__ ws,
                    int T)
{
  __shared__ unsigned h_lds[NPAIR];          // h_t as f16x2 pairs
  __shared__ unsigned wout_lds[2][NPAIR];    // this block's W_out rows, f16x2
  __shared__ float    x_lds[400];            // relu(start)

  const int tid  = threadIdx.x;
  const int b    = blockIdx.x;
  const int wave = tid >> 6;
  const int lane = tid & 63;
  const int G    = b * 4 + wave;             // global wave id, 0..1023
  const int i0   = 4 * G;                    // first of 4 owned h indices

  u64* buf0 = ws;            // [NPAIR] tagged h pairs, even steps
  u64* buf1 = ws + NPAIR;    // [NPAIR] odd steps
  // tag for h_t is (t+1); 0xAA poison never equals a valid tag.

  // ---- stage x = relu(start) and this block's W_out rows (f16) into LDS ----
  for (int p = tid; p < 400; p += NTHREADS) x_lds[p] = fmaxf(start[p], 0.0f);
  for (int s = 0; s < 2; ++s) {
    int row = 2 * b + s;
    if (row < 401) {
      for (int p = tid; p < NPAIR; p += NTHREADS) {
        float2 wv = *(const float2*)(W_out + (size_t)row * HDIM + 2 * p);
        UF u; u.h = (f16x2){(_Float16)wv.x, (_Float16)wv.y};
        wout_lds[s][p] = u.u;
      }
    }
  }
  __syncthreads();

  // ---- persistent W_hh fragment: 12 rows x 4 chunks of f16x16 = 384 VGPRs ----
  DECL_ROW(0)  DECL_ROW(1)  DECL_ROW(2)  DECL_ROW(3)
  DECL_ROW(4)  DECL_ROW(5)  DECL_ROW(6)  DECL_ROW(7)
  DECL_ROW(8)  DECL_ROW(9)  DECL_ROW(10) DECL_ROW(11)
  LOAD_ROW(0, 0, 0);  LOAD_ROW(1, 0, 1);  LOAD_ROW(2, 0, 2);  LOAD_ROW(3, 0, 3);   // r
  LOAD_ROW(4, 1, 0);  LOAD_ROW(5, 1, 1);  LOAD_ROW(6, 1, 2);  LOAD_ROW(7, 1, 3);   // z
  LOAD_ROW(8, 2, 0);  LOAD_ROW(9, 2, 1);  LOAD_ROW(10, 2, 2); LOAD_ROW(11, 2, 3);  // n

  // ---- gx = W_ih @ relu(start) + b_ih (+ b_hh folded for r,z) ----
  float gx0, gx1, gx2, gx3, gx4, gx5, gx6, gx7, gx8, gx9, gx10, gx11;
  GX_INIT(0, 0, 0);  GX_INIT(1, 0, 1);  GX_INIT(2, 0, 2);  GX_INIT(3, 0, 3);
  GX_INIT(4, 1, 0);  GX_INIT(5, 1, 1);  GX_INIT(6, 1, 2);  GX_INIT(7, 1, 3);
  GX_INIT(8, 2, 0);  GX_INIT(9, 2, 1);  GX_INIT(10, 2, 2); GX_INIT(11, 2, 3);
  const float bhn0 = b_hh[2 * HDIM + i0 + 0];
  const float bhn1 = b_hh[2 * HDIM + i0 + 1];
  const float bhn2 = b_hh[2 * HDIM + i0 + 2];
  const float bhn3 = b_hh[2 * HDIM + i0 + 3];

  // ---- h carry (fp32, owner registers) ----
  float h0 = enc_h[i0 + 0], h1 = enc_h[i0 + 1];
  float h2 = enc_h[i0 + 2], h3 = enc_h[i0 + 3];

  // publish h_0 (tag 1): wave owns exchange slots 2G (h0,h1) and 2G+1 (h2,h3)
  {
    UF ua, ub;
    ua.h = (f16x2){(_Float16)h0, (_Float16)h1};
    ub.h = (f16x2){(_Float16)h2, (_Float16)h3};
    u64 pay0 = ((u64)1u << 32) | (u64)ua.u;
    u64 pay1 = ((u64)1u << 32) | (u64)ub.u;
    if (lane < 2) st64(&buf0[2 * G + lane], lane ? pay1 : pay0);
  }

  // ---- main scan ----
  for (int t = 0; t < T; ++t) {
    u64* rd = (t & 1) ? buf1 : buf0;   // holds h_t, tag t+1
    u64* wr = (t & 1) ? buf0 : buf1;   // gets h_{t+1}, tag t+2
    const unsigned exp = (unsigned)(t + 1);

    // phase 1: tagged spin + broadcast -> LDS (this IS the grid barrier)
    {
      const int p0 = tid;                 const int p1 = tid + NTHREADS;
      const int p2 = tid + 2 * NTHREADS;  const int p3 = tid + 3 * NTHREADS;
      const int p4 = tid + 4 * NTHREADS;  const int p5 = tid + 5 * NTHREADS;
      const int p6 = tid + 6 * NTHREADS;  const int p7 = tid + 7 * NTHREADS;
      u64 v0, v1, v2, v3, v4, v5, v6, v7;
      for (;;) {
        v0 = ld64(rd + p0); v1 = ld64(rd + p1);
        v2 = ld64(rd + p2); v3 = ld64(rd + p3);
        v4 = ld64(rd + p4); v5 = ld64(rd + p5);
        v6 = ld64(rd + p6); v7 = ld64(rd + p7);
        if ((unsigned)(v0 >> 32) == exp && (unsigned)(v1 >> 32) == exp &&
            (unsigned)(v2 >> 32) == exp && (unsigned)(v3 >> 32) == exp &&
            (unsigned)(v4 >> 32) == exp && (unsigned)(v5 >> 32) == exp &&
            (unsigned)(v6 >> 32) == exp && (unsigned)(v7 >> 32) == exp) break;
        __builtin_amdgcn_s_sleep(1);
      }
      h_lds[p0] = (unsigned)v0; h_lds[p1] = (unsigned)v1;
      h_lds[p2] = (unsigned)v2; h_lds[p3] = (unsigned)v3;
      h_lds[p4] = (unsigned)v4; h_lds[p5] = (unsigned)v5;
      h_lds[p6] = (unsigned)v6; h_lds[p7] = (unsigned)v7;
    }
    __syncthreads();

    // gh = W_hh @ h_t : 12 rows per wave, h pairs reused across rows
    float a0 = 0.f, a1 = 0.f, a2 = 0.f, a3 = 0.f, a4 = 0.f, a5 = 0.f;
    float a6 = 0.f, a7 = 0.f, a8 = 0.f, a9 = 0.f, a10 = 0.f, a11 = 0.f;
    CHUNK_STEP(0); CHUNK_STEP(1); CHUNK_STEP(2); CHUNK_STEP(3);
    RED6(0)  RED6(1)  RED6(2)  RED6(3)  RED6(4)  RED6(5)
    RED6(6)  RED6(7)  RED6(8)  RED6(9)  RED6(10) RED6(11)

    // gates
    float r0 = sigmoidf_(gx0 + a0),  r1 = sigmoidf_(gx1 + a1);
    float r2 = sigmoidf_(gx2 + a2),  r3 = sigmoidf_(gx3 + a3);
    float z0 = sigmoidf_(gx4 + a4),  z1 = sigmoidf_(gx5 + a5);
    float z2 = sigmoidf_(gx6 + a6),  z3 = sigmoidf_(gx7 + a7);
    float n0 = tanhf_(gx8  + r0 * (a8  + bhn0));
    float n1 = tanhf_(gx9  + r1 * (a9  + bhn1));
    float n2 = tanhf_(gx10 + r2 * (a10 + bhn2));
    float n3 = tanhf_(gx11 + r3 * (a11 + bhn3));
    h0 = (1.0f - z0) * n0 + z0 * h0;
    h1 = (1.0f - z1) * n1 + z1 * h1;
    h2 = (1.0f - z2) * n2 + z2 * h2;
    h3 = (1.0f - z3) * n3 + z3 * h3;

    // publish h_{t+1} ASAP (tag t+2); all lanes hold the reduced sums
    {
      UF ua, ub;
      ua.h = (f16x2){(_Float16)h0, (_Float16)h1};
      ub.h = (f16x2){(_Float16)h2, (_Float16)h3};
      u64 tag = (u64)(unsigned)(t + 2) << 32;
      u64 pay0 = tag | (u64)ua.u;
      u64 pay1 = tag | (u64)ub.u;
      if (lane < 2) st64(&wr[2 * G + lane], lane ? pay1 : pay0);
    }

    // output for step t-1 (uses h_t, still in LDS) — hides in others' spin
    if (t > 0 && wave < 2) {
      int row = 2 * b + wave;
      if (row < 401) {
        float acc = 0.0f;
        #pragma unroll
        for (int j = 0; j < 32; ++j) {
          int p = lane + 64 * j;
          UF a, hh; a.u = wout_lds[wave][p]; hh.u = h_lds[p];
          acc = dot2f(a.h, hh.h, acc);
        }
        #pragma unroll
        for (int off = 32; off; off >>= 1) acc += __shfl_xor(acc, off, 64);
        if (lane == 0) {
          acc += b_out[row];
          if (row < 400) out[(size_t)(t - 1) * 400 + row] = tanhf_(acc);
          else           out[(size_t)400 * T + (t - 1)]   = sigmoidf_(acc);
        }
      }
    }
    __syncthreads();   // protect h_lds before next phase-1 overwrite
  }

  // ---- final output flush: o_{T-1} = W_out @ h_T (tag T+1) ----
  {
    u64* rd = (T & 1) ? buf1 : buf0;
    const unsigned exp = (unsigned)(T + 1);
    const int p0 = tid;                 const int p1 = tid + NTHREADS;
    const int p2 = tid + 2 * NTHREADS;  const int p3 = tid + 3 * NTHREADS;
    const int p4 = tid + 4 * NTHREADS;  const int p5 = tid + 5 * NTHREADS;
    const int p6 = tid + 6 * NTHREADS;  const int p7 = tid + 7 * NTHREADS;
    u64 v0, v1, v2, v3, v4, v5, v6, v7;
    for (;;) {
      v0 = ld64(rd + p0); v1 = ld64(rd + p1);
      v2 = ld64(rd + p2); v3 = ld64(rd + p3);
      v4 = ld64(rd + p4); v5 = ld64(rd + p5);
      v6 = ld64(rd + p6); v7 = ld64(rd + p7);
      if ((unsigned)(v0 >> 32) == exp && (unsigned)(v1 >> 32) == exp &&
          (unsigned)(v2 >> 32) == exp && (unsigned)(v3 >> 32) == exp &&
          (unsigned)(v4 >> 32) == exp && (unsigned)(v5 >> 32) == exp &&
          (unsigned)(v6 >> 32) == exp && (unsigned)(v7 >> 32) == exp) break;
      __builtin_amdgcn_s_sleep(1);
    }
    h_lds[p0] = (unsigned)v0; h_lds[p1] = (unsigned)v1;
    h_lds[p2] = (unsigned)v2; h_lds[p3] = (unsigned)v3;
    h_lds[p4] = (unsigned)v4; h_lds[p5] = (unsigned)v5;
    h_lds[p6] = (unsigned)v6; h_lds[p7] = (unsigned)v7;
    __syncthreads();
    if (wave < 2) {
      int row = 2 * b + wave;
      if (row < 401) {
        float acc = 0.0f;
        #pragma unroll
        for (int j = 0; j < 32; ++j) {
          int p = lane + 64 * j;
          UF a, hh; a.u = wout_lds[wave][p]; hh.u = h_lds[p];
          acc = dot2f(a.h, hh.h, acc);
        }
        #pragma unroll
        for (int off = 32; off; off >>= 1) acc += __shfl_xor(acc, off, 64);
        if (lane == 0) {
          acc += b_out[row];
          if (row < 400) out[(size_t)(T - 1) * 400 + row] = tanhf_(acc);
          else           out[(size_t)400 * T + (T - 1)]   = sigmoidf_(acc);
        }
      }
    }
  }
}

extern "C" void kernel_launch(void* const* d_in, const int* in_sizes, int n_in,
                              void* d_out, int out_size, void* d_ws, size_t ws_size,
                              hipStream_t stream) {
  (void)in_sizes; (void)n_in; (void)ws_size;
  const float* start = (const float*)d_in[0];
  const float* enc_h = (const float*)d_in[1];
  const float* W_ih  = (const float*)d_in[2];
  const float* W_hh  = (const float*)d_in[3];
  const float* b_ih  = (const float*)d_in[4];
  const float* b_hh  = (const float*)d_in[5];
  const float* W_out = (const float*)d_in[6];
  const float* b_out = (const float*)d_in[7];
  float* out = (float*)d_out;
  u64* ws = (u64*)d_ws;

  int T = out_size / 401;   // outputs T*400 + stops T

  gru_persistent<<<NBLOCKS, NTHREADS, 0, stream>>>(
      start, enc_h, W_ih, W_hh, b_ih, b_hh, W_out, b_out, out, ws, T);
}